// Round 1
// baseline (883.197 us; speedup 1.0000x reference)
//
#include <hip/hip_runtime.h>
#include <hip/hip_bf16.h>

typedef __attribute__((ext_vector_type(4))) float f32x4;
typedef __attribute__((ext_vector_type(8))) short s16x8;
typedef __attribute__((ext_vector_type(4))) unsigned short u16x4;

// B=16, L=512, D=512, H=8, DK=DV=64, TEMP=8
// ws layout (bf16 halves): qh[16][8][512][64] | kh same | vh same | vhT[16][8][64][512] | ofl[16][262144]
// each region 4,194,304 halves = 8 MB; total 40 MB of d_ws.

__device__ __forceinline__ unsigned short f2bf(float f) {
    unsigned int u = __builtin_bit_cast(unsigned int, f);
    u += 0x7fffu + ((u >> 16) & 1u);          // round-to-nearest-even
    return (unsigned short)(u >> 16);
}

// ---------------- projections: qh/kh/vh = X @ W^T + b, bf16 out -----------------
__global__ __launch_bounds__(256) void proj_kernel(
    const float* __restrict__ q, const float* __restrict__ k, const float* __restrict__ v,
    const float* __restrict__ Wq, const float* __restrict__ bq,
    const float* __restrict__ Wk, const float* __restrict__ bk,
    const float* __restrict__ Wv, const float* __restrict__ bv,
    unsigned short* __restrict__ qh, unsigned short* __restrict__ kh, unsigned short* __restrict__ vh)
{
    const int z = blockIdx.z;
    const float* X    = (z == 0) ? q  : (z == 1) ? k  : v;
    const float* W    = (z == 0) ? Wq : (z == 1) ? Wk : Wv;
    const float* bias = (z == 0) ? bq : (z == 1) ? bk : bv;
    unsigned short* out = (z == 0) ? qh : (z == 1) ? kh : vh;

    __shared__ __align__(16) unsigned short lA[128 * 40];  // 128 rows, 32 halves + pad 8
    __shared__ __align__(16) unsigned short lB[128 * 40];

    const int t = threadIdx.x;
    const int m0 = blockIdx.x * 128;
    const int n0 = blockIdx.y * 128;
    const int wave = t >> 6, lane = t & 63, quad = lane >> 4, l16 = lane & 15;
    const int wm = (wave >> 1) * 64, wn = (wave & 1) * 64;

    f32x4 acc[4][4];
#pragma unroll
    for (int i = 0; i < 4; i++)
#pragma unroll
        for (int j = 0; j < 4; j++) acc[i][j] = (f32x4){0.f, 0.f, 0.f, 0.f};

    for (int k0 = 0; k0 < 512; k0 += 32) {
#pragma unroll
        for (int it = 0; it < 4; it++) {
            int idx = it * 256 + t;
            int row = idx >> 3, c = (idx & 7) * 4;
            f32x4 xa = *(const f32x4*)(X + (size_t)(m0 + row) * 512 + k0 + c);
            u16x4 pa = {f2bf(xa.x), f2bf(xa.y), f2bf(xa.z), f2bf(xa.w)};
            *(u16x4*)&lA[row * 40 + c] = pa;
            f32x4 xb = *(const f32x4*)(W + (size_t)(n0 + row) * 512 + k0 + c);
            u16x4 pb = {f2bf(xb.x), f2bf(xb.y), f2bf(xb.z), f2bf(xb.w)};
            *(u16x4*)&lB[row * 40 + c] = pb;
        }
        __syncthreads();
        s16x8 af[4], bm[4];
#pragma unroll
        for (int i = 0; i < 4; i++) af[i] = *(const s16x8*)&lA[(wm + i * 16 + l16) * 40 + quad * 8];
#pragma unroll
        for (int j = 0; j < 4; j++) bm[j] = *(const s16x8*)&lB[(wn + j * 16 + l16) * 40 + quad * 8];
#pragma unroll
        for (int i = 0; i < 4; i++)
#pragma unroll
            for (int j = 0; j < 4; j++)
                acc[i][j] = __builtin_amdgcn_mfma_f32_16x16x32_bf16(af[i], bm[j], acc[i][j], 0, 0, 0);
        __syncthreads();
    }
    // epilogue: +bias, store bf16 to [b][h][l][d]
#pragma unroll
    for (int j = 0; j < 4; j++) {
        int n = n0 + wn + j * 16 + l16;
        float bb = bias[n];
        int h = n >> 6, d = n & 63;
#pragma unroll
        for (int i = 0; i < 4; i++) {
#pragma unroll
            for (int r = 0; r < 4; r++) {
                int m = m0 + wm + i * 16 + quad * 4 + r;
                int b = m >> 9, l = m & 511;
                out[(size_t)((b * 8 + h) * 512 + l) * 64 + d] = f2bf(acc[i][j][r] + bb);
            }
        }
    }
}

// ---------------- vh [bh][key][d] -> vhT [bh][d][key] -----------------
__global__ __launch_bounds__(256) void transpose_v(const unsigned short* __restrict__ vh,
                                                   unsigned short* __restrict__ vhT)
{
    __shared__ unsigned short lT[64 * 72];
    const int bh = blockIdx.x;          // b*8+h
    const int k0 = blockIdx.y * 64;
    const int t = threadIdx.x;
    const unsigned short* src = vh + (size_t)bh * 32768;
    unsigned short* dst = vhT + (size_t)bh * 32768;
#pragma unroll
    for (int it = 0; it < 4; it++) {
        int idx = it * 256 + t;
        int row = idx >> 4, c = (idx & 15) * 4;
        *(u16x4*)&lT[row * 72 + c] = *(const u16x4*)(src + (size_t)(k0 + row) * 64 + c);
    }
    __syncthreads();
#pragma unroll
    for (int it = 0; it < 16; it++) {
        int idx = it * 256 + t;
        int d = idx >> 6, kk = idx & 63;
        dst[(size_t)d * 512 + k0 + kk] = lT[kk * 72 + d];
    }
}

// ---------------- init output with bias -----------------
__global__ void init_out(float* __restrict__ out, const float* __restrict__ bf)
{
    int i = blockIdx.x * 256 + threadIdx.x;
    if (i < 8192) out[i] = bf[i & 511];
}

// ---------------- fused attention per (h,b,64 q rows) -----------------
__global__ __launch_bounds__(256) void attn_kernel(
    const unsigned short* __restrict__ qh, const unsigned short* __restrict__ kh,
    const unsigned short* __restrict__ vhT,
    float* __restrict__ dout, unsigned short* __restrict__ ofl)
{
    __shared__ __align__(16) unsigned short lp[4][16][520];  // per-wave P tile, bf16
    const int bh = blockIdx.y;          // h*16 + b  (matches attn_flat row order h*B+b)
    const int h = bh >> 4, b = bh & 15;
    const int q0 = blockIdx.x * 64;
    const int t = threadIdx.x;
    const int w = t >> 6, lane = t & 63, quad = lane >> 4, l16 = lane & 15;
    const size_t base = (size_t)(b * 8 + h) * 32768;
    const unsigned short* qb = qh + base;
    const unsigned short* kb = kh + base;
    const unsigned short* vb = vhT + base;

    const int qrow = q0 + w * 16 + l16;
    s16x8 aq0 = *(const s16x8*)(qb + (size_t)qrow * 64 + quad * 8);
    s16x8 aq1 = *(const s16x8*)(qb + (size_t)qrow * 64 + 32 + quad * 8);

    f32x4 acc[32];
#pragma unroll
    for (int tt = 0; tt < 32; tt++) acc[tt] = (f32x4){0.f, 0.f, 0.f, 0.f};

    // scores: 16 q-rows x 512 keys per wave, fp32 accumulate
#pragma unroll
    for (int tt = 0; tt < 32; tt++) {
        const unsigned short* kp = kb + (size_t)(tt * 16 + l16) * 64 + quad * 8;
        s16x8 b0 = *(const s16x8*)kp;
        s16x8 b1 = *(const s16x8*)(kp + 32);
        acc[tt] = __builtin_amdgcn_mfma_f32_16x16x32_bf16(aq0, b0, acc[tt], 0, 0, 0);
        acc[tt] = __builtin_amdgcn_mfma_f32_16x16x32_bf16(aq1, b1, acc[tt], 0, 0, 0);
    }

    // softmax over keys (row = quad*4+r, cols spread over 16 lanes of the quad)
    float mx[4] = {-1e30f, -1e30f, -1e30f, -1e30f};
#pragma unroll
    for (int tt = 0; tt < 32; tt++)
#pragma unroll
        for (int r = 0; r < 4; r++) {
            float s = acc[tt][r] * 0.125f;   // /sqrt(64)
            acc[tt][r] = s;
            mx[r] = fmaxf(mx[r], s);
        }
#pragma unroll
    for (int r = 0; r < 4; r++) {
        float m = mx[r];
        m = fmaxf(m, __shfl_xor(m, 1));
        m = fmaxf(m, __shfl_xor(m, 2));
        m = fmaxf(m, __shfl_xor(m, 4));
        m = fmaxf(m, __shfl_xor(m, 8));
        mx[r] = m;
    }
    float sm[4] = {0.f, 0.f, 0.f, 0.f};
#pragma unroll
    for (int tt = 0; tt < 32; tt++)
#pragma unroll
        for (int r = 0; r < 4; r++) {
            float e = __expf(acc[tt][r] - mx[r]);
            acc[tt][r] = e;
            sm[r] += e;
        }
    float inv[4];
#pragma unroll
    for (int r = 0; r < 4; r++) {
        float s = sm[r];
        s += __shfl_xor(s, 1);
        s += __shfl_xor(s, 2);
        s += __shfl_xor(s, 4);
        s += __shfl_xor(s, 8);
        inv[r] = 1.0f / s;
    }

    // write attn (fp32, exact output) + bf16 copy to LDS for PV A-operand
    float* attn_out = dout + 8192;
#pragma unroll
    for (int r = 0; r < 4; r++) {
        int qq = q0 + w * 16 + quad * 4 + r;
        float* rp = attn_out + (size_t)bh * 262144 + (size_t)qq * 512 + l16;
        float iv = inv[r];
#pragma unroll
        for (int tt = 0; tt < 32; tt++) {
            float p = acc[tt][r] * iv;
            rp[tt * 16] = p;
            lp[w][quad * 4 + r][tt * 16 + l16] = f2bf(p);
        }
    }
    // same-wave LDS RAW: DS ops execute in order within a wave, no barrier needed.

    // PV: out[q][d] = P @ V  (A from LDS, B from vhT [d][key])
    f32x4 oacc[4];
#pragma unroll
    for (int j = 0; j < 4; j++) oacc[j] = (f32x4){0.f, 0.f, 0.f, 0.f};
#pragma unroll
    for (int ks = 0; ks < 16; ks++) {
        s16x8 pa = *(const s16x8*)&lp[w][l16][ks * 32 + quad * 8];
#pragma unroll
        for (int j = 0; j < 4; j++) {
            s16x8 bv = *(const s16x8*)(vb + (size_t)(j * 16 + l16) * 512 + ks * 32 + quad * 8);
            oacc[j] = __builtin_amdgcn_mfma_f32_16x16x32_bf16(pa, bv, oacc[j], 0, 0, 0);
        }
    }
    // store out_flat bf16: ofl[b][(q*8+h)*64+d]
#pragma unroll
    for (int j = 0; j < 4; j++) {
#pragma unroll
        for (int r = 0; r < 4; r++) {
            int qq = q0 + w * 16 + quad * 4 + r;
            int d = j * 16 + l16;
            ofl[(size_t)b * 262144 + (size_t)(qq * 8 + h) * 64 + d] = f2bf(oacc[j][r]);
        }
    }
}

// ---------------- dynamic fc: out[16,512] += ofl[16,262144] @ Wf^T -----------------
__global__ __launch_bounds__(512) void fc_kernel(
    const unsigned short* __restrict__ ofl, const float* __restrict__ Wf,
    float* __restrict__ out)
{
    __shared__ __align__(16) float red[8][4][64][4];  // 32 KB
    const int t = threadIdx.x;
    const int w = t >> 6, lane = t & 63, quad = lane >> 4, l16 = lane & 15;
    const int n0 = blockIdx.x * 64;
    const int kbase = blockIdx.y * 4096 + w * 512;

    f32x4 acc[4];
#pragma unroll
    for (int j = 0; j < 4; j++) acc[j] = (f32x4){0.f, 0.f, 0.f, 0.f};

#pragma unroll
    for (int ks = 0; ks < 16; ks++) {
        int kk = kbase + ks * 32;
        s16x8 af = *(const s16x8*)(ofl + (size_t)l16 * 262144 + kk + quad * 8);
#pragma unroll
        for (int j = 0; j < 4; j++) {
            const float* wp = Wf + (size_t)(n0 + j * 16 + l16) * 262144 + kk + quad * 8;
            f32x4 w0 = *(const f32x4*)wp;
            f32x4 w1 = *(const f32x4*)(wp + 4);
            s16x8 bv = {(short)f2bf(w0.x), (short)f2bf(w0.y), (short)f2bf(w0.z), (short)f2bf(w0.w),
                        (short)f2bf(w1.x), (short)f2bf(w1.y), (short)f2bf(w1.z), (short)f2bf(w1.w)};
            acc[j] = __builtin_amdgcn_mfma_f32_16x16x32_bf16(af, bv, acc[j], 0, 0, 0);
        }
    }
#pragma unroll
    for (int j = 0; j < 4; j++) *(f32x4*)&red[w][j][lane][0] = acc[j];
    __syncthreads();
    if (t < 256) {
        int j = t >> 6, ln = t & 63;
        f32x4 s = (f32x4){0.f, 0.f, 0.f, 0.f};
#pragma unroll
        for (int wv = 0; wv < 8; wv++) s += *(const f32x4*)&red[wv][j][ln][0];
        int qd = ln >> 4, lo = ln & 15;
        int o = n0 + j * 16 + lo;
#pragma unroll
        for (int r = 0; r < 4; r++) atomicAdd(&out[(qd * 4 + r) * 512 + o], s[r]);
    }
}

extern "C" void kernel_launch(void* const* d_in, const int* in_sizes, int n_in,
                              void* d_out, int out_size, void* d_ws, size_t ws_size,
                              hipStream_t stream)
{
    const float* q  = (const float*)d_in[0];
    const float* k  = (const float*)d_in[1];
    const float* v  = (const float*)d_in[2];
    const float* Wq = (const float*)d_in[3];
    const float* bq = (const float*)d_in[4];
    const float* Wk = (const float*)d_in[5];
    const float* bk = (const float*)d_in[6];
    const float* Wv = (const float*)d_in[7];
    const float* bv = (const float*)d_in[8];
    const float* Wf = (const float*)d_in[9];
    const float* bf = (const float*)d_in[10];

    unsigned short* qh  = (unsigned short*)d_ws;
    unsigned short* kh  = qh  + 4194304;
    unsigned short* vh  = kh  + 4194304;
    unsigned short* vhT = vh  + 4194304;
    unsigned short* ofl = vhT + 4194304;
    float* out = (float*)d_out;

    hipLaunchKernelGGL(proj_kernel, dim3(64, 4, 3), dim3(256), 0, stream,
                       q, k, v, Wq, bq, Wk, bk, Wv, bv, qh, kh, vh);
    hipLaunchKernelGGL(transpose_v, dim3(128, 8), dim3(256), 0, stream, vh, vhT);
    hipLaunchKernelGGL(init_out, dim3(32), dim3(256), 0, stream, out, bf);
    hipLaunchKernelGGL(attn_kernel, dim3(8, 128), dim3(256), 0, stream, qh, kh, vhT, out, ofl);
    hipLaunchKernelGGL(fc_kernel, dim3(8, 64), dim3(512), 0, stream, ofl, Wf, out);
}